// Round 15
// baseline (1170.115 us; speedup 1.0000x reference)
//
#include <hip/hip_runtime.h>
#include <hip/hip_cooperative_groups.h>
#include <hip/hip_fp16.h>
#include <math.h>

#define N_NODES    1000000
#define N_EDGES    16000000
#define NUM_GRAPHS 64
#define LATENT     128

// ws layout (doubles):
// [0..4): legacy scalars: [1] S1 [2] S2 (legacy edge mode)
// node shadow region: 8 copies at SH_BASE + s*SH_STRIDE:
//   +0 recon, +1 kl, +2..66 gx, +66..130 gy, +130..194 cnt
// edge shadows (big mode): 16 line-separated {S1,S2} pairs at EDGE_SH_BASE + sh*8
// packed half2 table at byte offset 16384 (big mode) or 2048 (legacy mode)
#define SH_BASE        8
#define SH_STRIDE      200
#define NSHADOW_BIG    8
#define EDGE_SH_BASE   1608   // 8 + 8*200
#define EDGE_NSHADOW   16
#define WS_DOUBLES_TOT 1736   // 1608 + 16*8
#define WS_DOUBLES_LEGACY 208
#define PACKED_OFFSET_BIG    16384
#define PACKED_OFFSET_LEGACY 2048

typedef int vint4 __attribute__((ext_vector_type(4)));
namespace cg = cooperative_groups;

// ===================== FUSED COOPERATIVE KERNEL =====================
// phases: 0 zero-ws | sync | 1 node+KL (+packed table) | sync | 2 edge |
// sync | 3 finalize (thread 0). One dispatch replaces 4 — and its dur
// finally exposes the node phase's cost (fused_dur - 156 - ~10).
__global__ void __launch_bounds__(256, 8)
fused_all(const float2* __restrict__ pred,
          const float2* __restrict__ targ,
          const int* __restrict__ ei,
          const int* __restrict__ batch,
          const float* __restrict__ mu,
          const float* __restrict__ logvar,
          const int* __restrict__ epoch_p,
          float* __restrict__ out,
          double* __restrict__ ws,
          unsigned* __restrict__ packed) {
    cg::grid_group grid = cg::this_grid();

    __shared__ float sgx[NUM_GRAPHS];
    __shared__ float sgy[NUM_GRAPHS];
    __shared__ int   scnt[NUM_GRAPHS];
    __shared__ double smem[8];
    __shared__ double smem2[8];

    const int tid  = threadIdx.x;
    const int gtid = blockIdx.x * blockDim.x + tid;
    const int nthr = gridDim.x * blockDim.x;
    const int lane = tid & 63;
    const int wid  = tid >> 6;

    // ---- phase 0: zero ws accumulators + LDS ----
    for (int t = gtid; t < WS_DOUBLES_TOT; t += nthr) ws[t] = 0.0;
    for (int g = tid; g < NUM_GRAPHS; g += blockDim.x) {
        sgx[g] = 0.f; sgy[g] = 0.f; scnt[g] = 0;
    }
    __syncthreads();
    grid.sync();

    // ---- phase 1: node + KL (wave-contiguous chunks; per-thread
    // accumulators flushed on graph change / at end) ----
    double* shbase = ws + SH_BASE +
                     (size_t)(blockIdx.x & (NSHADOW_BIG - 1)) * SH_STRIDE;
    {
        const int nwaves = nthr >> 6;
        const int gwave  = gtid >> 6;
        const int chunk  = (N_NODES + nwaves - 1) / nwaves;
        const int start  = gwave * chunk;
        const int end    = (start + chunk < N_NODES) ? (start + chunk)
                                                     : N_NODES;
        float recon = 0.f, sx = 0.f, sy = 0.f;
        int cnt = 0, bcur = -1;
        for (int n0 = start; n0 < end; n0 += 64) {
            const int n = n0 + lane;
            if (n < end) {
                float2 p = pred[n];
                float2 t = targ[n];
                float dx = p.x - t.x, dy = p.y - t.y;
                recon += dx * dx + dy * dy;
                __half2 h = __floats2half2_rn(p.x, p.y);
                packed[n] = *reinterpret_cast<unsigned*>(&h);
                int b = batch[n];
                if (b != bcur) {
                    if (cnt != 0) {
                        atomicAdd(&sgx[bcur], sx);
                        atomicAdd(&sgy[bcur], sy);
                        atomicAdd(&scnt[bcur], cnt);
                    }
                    bcur = b; sx = 0.f; sy = 0.f; cnt = 0;
                }
                sx += p.x; sy += p.y; ++cnt;
            }
        }
        if (cnt != 0) {
            atomicAdd(&sgx[bcur], sx);
            atomicAdd(&sgy[bcur], sy);
            atomicAdd(&scnt[bcur], cnt);
        }

        double r = (double)recon;
        #pragma unroll
        for (int off = 32; off > 0; off >>= 1) r += __shfl_down(r, off);
        if (lane == 0) smem[wid] = r;
        __syncthreads();
        if (tid == 0) {
            double tot = 0.0;
            const int nw = blockDim.x >> 6;
            for (int w = 0; w < nw; ++w) tot += smem[w];
            atomicAdd(&shbase[0], tot);
        }
        for (int g = tid; g < NUM_GRAPHS; g += blockDim.x) {
            if (scnt[g] != 0) {
                atomicAdd(&shbase[2 + g],   (double)sgx[g]);
                atomicAdd(&shbase[66 + g],  (double)sgy[g]);
                atomicAdd(&shbase[130 + g], (double)scnt[g]);
            }
        }
        if (blockIdx.x == 0) {
            double s = 0.0;
            for (int t = tid; t < NUM_GRAPHS * LATENT; t += blockDim.x) {
                float m = mu[t], lv = logvar[t];
                s += (double)(1.0f + lv - m * m - expf(lv));
            }
            #pragma unroll
            for (int off = 32; off > 0; off >>= 1) s += __shfl_down(s, off);
            __syncthreads();
            if (lane == 0) smem[wid] = s;
            __syncthreads();
            if (tid == 0) {
                double tot = 0.0;
                const int nw = blockDim.x >> 6;
                for (int w = 0; w < nw; ++w) tot += smem[w];
                atomicAdd(&shbase[1], tot);
            }
        }
    }
    grid.sync();   // packed table complete + device-visible

    // ---- phase 2: edge (exact round-9 measured-156µs loop) ----
    {
        float s1 = 0.f, s2 = 0.f;
        const int stride = nthr;
        const int ngroups = N_EDGES / 4;
        const vint4* eia = (const vint4*)ei;
        const vint4* eib = (const vint4*)(ei + N_EDGES);

        int g = gtid;
        if (g < ngroups) {
            vint4 a = __builtin_nontemporal_load(eia + g);
            vint4 b = __builtin_nontemporal_load(eib + g);
            while (true) {
                unsigned pa0 = packed[a.x], pb0 = packed[b.x];
                unsigned pa1 = packed[a.y], pb1 = packed[b.y];
                unsigned pa2 = packed[a.z], pb2 = packed[b.z];
                unsigned pa3 = packed[a.w], pb3 = packed[b.w];

                const int gn = g + stride;
                const bool more = gn < ngroups;
                vint4 an = {0, 0, 0, 0}, bn = {0, 0, 0, 0};
                if (more) {
                    an = __builtin_nontemporal_load(eia + gn);
                    bn = __builtin_nontemporal_load(eib + gn);
                }
                {
                    __half2 ha = *reinterpret_cast<__half2*>(&pa0);
                    __half2 hb = *reinterpret_cast<__half2*>(&pb0);
                    float2 fa = __half22float2(ha);
                    float2 fb = __half22float2(hb);
                    float dx = fa.x - fb.x, dy = fa.y - fb.y;
                    float l2 = dx * dx + dy * dy;
                    s2 += l2; s1 += sqrtf(l2);
                }
                {
                    __half2 ha = *reinterpret_cast<__half2*>(&pa1);
                    __half2 hb = *reinterpret_cast<__half2*>(&pb1);
                    float2 fa = __half22float2(ha);
                    float2 fb = __half22float2(hb);
                    float dx = fa.x - fb.x, dy = fa.y - fb.y;
                    float l2 = dx * dx + dy * dy;
                    s2 += l2; s1 += sqrtf(l2);
                }
                {
                    __half2 ha = *reinterpret_cast<__half2*>(&pa2);
                    __half2 hb = *reinterpret_cast<__half2*>(&pb2);
                    float2 fa = __half22float2(ha);
                    float2 fb = __half22float2(hb);
                    float dx = fa.x - fb.x, dy = fa.y - fb.y;
                    float l2 = dx * dx + dy * dy;
                    s2 += l2; s1 += sqrtf(l2);
                }
                {
                    __half2 ha = *reinterpret_cast<__half2*>(&pa3);
                    __half2 hb = *reinterpret_cast<__half2*>(&pb3);
                    float2 fa = __half22float2(ha);
                    float2 fb = __half22float2(hb);
                    float dx = fa.x - fb.x, dy = fa.y - fb.y;
                    float l2 = dx * dx + dy * dy;
                    s2 += l2; s1 += sqrtf(l2);
                }
                if (!more) break;
                g = gn; a = an; b = bn;
            }
        }
        double r1 = (double)s1, r2 = (double)s2;
        #pragma unroll
        for (int off = 32; off > 0; off >>= 1) {
            r1 += __shfl_down(r1, off);
            r2 += __shfl_down(r2, off);
        }
        if (lane == 0) { smem[wid] = r1; smem2[wid] = r2; }
        __syncthreads();
        if (tid == 0) {
            double t1 = 0.0, t2 = 0.0;
            const int nw = blockDim.x >> 6;
            for (int w = 0; w < nw; ++w) { t1 += smem[w]; t2 += smem2[w]; }
            const int sh = blockIdx.x & (EDGE_NSHADOW - 1);
            atomicAdd(&ws[EDGE_SH_BASE + sh * 8 + 0], t1);
            atomicAdd(&ws[EDGE_SH_BASE + sh * 8 + 1], t2);
        }
    }
    grid.sync();

    // ---- phase 3: finalize ----
    if (gtid == 0) {
        double recon_sum = 0.0, kl_sum = 0.0;
        for (int s = 0; s < NSHADOW_BIG; ++s) {
            recon_sum += ws[SH_BASE + s * SH_STRIDE + 0];
            kl_sum    += ws[SH_BASE + s * SH_STRIDE + 1];
        }
        double S1 = 0.0, S2 = 0.0;
        for (int s = 0; s < EDGE_NSHADOW; ++s) {
            S1 += ws[EDGE_SH_BASE + s * 8 + 0];
            S2 += ws[EDGE_SH_BASE + s * 8 + 1];
        }
        double recon = recon_sum / (2.0 * (double)N_NODES);
        double lap  = S2 / (double)N_EDGES;
        double arap = (S2 - S1 * S1 / (double)N_EDGES)
                      / ((double)N_EDGES - 1.0);
        double drift = 0.0;
        for (int g = 0; g < NUM_GRAPHS; ++g) {
            double c = 0.0, sx = 0.0, sy = 0.0;
            for (int s = 0; s < NSHADOW_BIG; ++s) {
                c  += ws[SH_BASE + s * SH_STRIDE + 130 + g];
                sx += ws[SH_BASE + s * SH_STRIDE + 2 + g];
                sy += ws[SH_BASE + s * SH_STRIDE + 66 + g];
            }
            double mx = sx / c, my = sy / c;
            drift += mx * mx + my * my;
        }
        drift /= (double)NUM_GRAPHS;
        double kl = -0.5 * kl_sum / (double)NUM_GRAPHS;
        int epoch = *epoch_p;
        double beta = (epoch < 10) ? ((double)epoch / 10.0) : 1.0;
        out[0] = (float)(recon + 0.1 * lap + 0.01 * drift + 0.1 * arap
                         + beta * kl);
    }
}

// ===================== LEGACY 4-LAUNCH FALLBACK =====================
__global__ void init_ws(double* ws, int n) {
    int t = blockIdx.x * blockDim.x + threadIdx.x;
    if (t < n) ws[t] = 0.0;
}

__global__ void node_kl_pass(const float2* __restrict__ pred,
                             const float2* __restrict__ targ,
                             const int*    __restrict__ batch,
                             const float*  __restrict__ mu,
                             const float*  __restrict__ logvar,
                             double* __restrict__ ws,
                             unsigned* __restrict__ packed,  // may be null
                             int ns) {
    __shared__ float sgx[NUM_GRAPHS];
    __shared__ float sgy[NUM_GRAPHS];
    __shared__ int   scnt[NUM_GRAPHS];
    __shared__ double smem[8];

    for (int g = threadIdx.x; g < NUM_GRAPHS; g += blockDim.x) {
        sgx[g] = 0.f; sgy[g] = 0.f; scnt[g] = 0;
    }
    __syncthreads();

    double* shbase = ws + SH_BASE + (size_t)(blockIdx.x & (ns - 1)) * SH_STRIDE;

    const int lane   = threadIdx.x & 63;
    const int wid    = threadIdx.x >> 6;
    const int nwaves = (gridDim.x * blockDim.x) >> 6;
    const int gwave  = (blockIdx.x * blockDim.x + threadIdx.x) >> 6;
    const int chunk  = (N_NODES + nwaves - 1) / nwaves;
    const int start  = gwave * chunk;
    const int end    = (start + chunk < N_NODES) ? (start + chunk) : N_NODES;

    float recon = 0.f, sx = 0.f, sy = 0.f;
    int cnt = 0, bcur = -1;
    for (int n0 = start; n0 < end; n0 += 64) {
        const int n = n0 + lane;
        if (n < end) {
            float2 p = pred[n];
            float2 t = targ[n];
            float dx = p.x - t.x, dy = p.y - t.y;
            recon += dx * dx + dy * dy;
            if (packed) {
                __half2 h = __floats2half2_rn(p.x, p.y);
                packed[n] = *reinterpret_cast<unsigned*>(&h);
            }
            int b = batch[n];
            if (b != bcur) {
                if (cnt != 0) {
                    atomicAdd(&sgx[bcur], sx);
                    atomicAdd(&sgy[bcur], sy);
                    atomicAdd(&scnt[bcur], cnt);
                }
                bcur = b; sx = 0.f; sy = 0.f; cnt = 0;
            }
            sx += p.x; sy += p.y; ++cnt;
        }
    }
    if (cnt != 0) {
        atomicAdd(&sgx[bcur], sx);
        atomicAdd(&sgy[bcur], sy);
        atomicAdd(&scnt[bcur], cnt);
    }

    double r = (double)recon;
    #pragma unroll
    for (int off = 32; off > 0; off >>= 1) r += __shfl_down(r, off);
    if (lane == 0) smem[wid] = r;
    __syncthreads();
    if (threadIdx.x == 0) {
        double tot = 0.0;
        const int nw = blockDim.x >> 6;
        for (int w = 0; w < nw; ++w) tot += smem[w];
        atomicAdd(&shbase[0], tot);
    }
    for (int g = threadIdx.x; g < NUM_GRAPHS; g += blockDim.x) {
        if (scnt[g] != 0) {
            atomicAdd(&shbase[2 + g],   (double)sgx[g]);
            atomicAdd(&shbase[66 + g],  (double)sgy[g]);
            atomicAdd(&shbase[130 + g], (double)scnt[g]);
        }
    }
    if (blockIdx.x == 0) {
        double s = 0.0;
        for (int t = threadIdx.x; t < NUM_GRAPHS * LATENT; t += blockDim.x) {
            float m = mu[t], lv = logvar[t];
            s += (double)(1.0f + lv - m * m - expf(lv));
        }
        #pragma unroll
        for (int off = 32; off > 0; off >>= 1) s += __shfl_down(s, off);
        __syncthreads();
        if (lane == 0) smem[wid] = s;
        __syncthreads();
        if (threadIdx.x == 0) {
            double tot = 0.0;
            const int nw = blockDim.x >> 6;
            for (int w = 0; w < nw; ++w) tot += smem[w];
            atomicAdd(&shbase[1], tot);
        }
    }
}

__device__ __forceinline__ void edge_flush(float s1, float s2, double* ws,
                                           int edge_mode,
                                           double* smem1, double* smem2) {
    double r1 = (double)s1, r2 = (double)s2;
    #pragma unroll
    for (int off = 32; off > 0; off >>= 1) {
        r1 += __shfl_down(r1, off);
        r2 += __shfl_down(r2, off);
    }
    const int lane = threadIdx.x & 63;
    const int wid  = threadIdx.x >> 6;
    if (lane == 0) { smem1[wid] = r1; smem2[wid] = r2; }
    __syncthreads();
    if (threadIdx.x == 0) {
        double t1 = 0.0, t2 = 0.0;
        const int nw = blockDim.x >> 6;
        for (int w = 0; w < nw; ++w) { t1 += smem1[w]; t2 += smem2[w]; }
        if (edge_mode) {
            const int sh = blockIdx.x & (EDGE_NSHADOW - 1);
            atomicAdd(&ws[EDGE_SH_BASE + sh * 8 + 0], t1);
            atomicAdd(&ws[EDGE_SH_BASE + sh * 8 + 1], t2);
        } else {
            atomicAdd(&ws[1], t1);
            atomicAdd(&ws[2], t2);
        }
    }
}

__global__ void edge_pass_packed(const unsigned* __restrict__ packed,
                                 const int* __restrict__ ei,
                                 double* __restrict__ ws,
                                 int edge_mode) {
    __shared__ double smem1[8];
    __shared__ double smem2[8];

    float s1 = 0.f, s2 = 0.f;
    const int gid = blockIdx.x * blockDim.x + threadIdx.x;
    const int stride = gridDim.x * blockDim.x;
    const int ngroups = N_EDGES / 4;
    const vint4* eia = (const vint4*)ei;
    const vint4* eib = (const vint4*)(ei + N_EDGES);

    int g = gid;
    if (g < ngroups) {
        vint4 a = __builtin_nontemporal_load(eia + g);
        vint4 b = __builtin_nontemporal_load(eib + g);
        while (true) {
            unsigned pa0 = packed[a.x], pb0 = packed[b.x];
            unsigned pa1 = packed[a.y], pb1 = packed[b.y];
            unsigned pa2 = packed[a.z], pb2 = packed[b.z];
            unsigned pa3 = packed[a.w], pb3 = packed[b.w];

            const int gn = g + stride;
            const bool more = gn < ngroups;
            vint4 an = {0, 0, 0, 0}, bn = {0, 0, 0, 0};
            if (more) {
                an = __builtin_nontemporal_load(eia + gn);
                bn = __builtin_nontemporal_load(eib + gn);
            }
            {
                __half2 ha = *reinterpret_cast<__half2*>(&pa0);
                __half2 hb = *reinterpret_cast<__half2*>(&pb0);
                float2 fa = __half22float2(ha);
                float2 fb = __half22float2(hb);
                float dx = fa.x - fb.x, dy = fa.y - fb.y;
                float l2 = dx * dx + dy * dy;
                s2 += l2; s1 += sqrtf(l2);
            }
            {
                __half2 ha = *reinterpret_cast<__half2*>(&pa1);
                __half2 hb = *reinterpret_cast<__half2*>(&pb1);
                float2 fa = __half22float2(ha);
                float2 fb = __half22float2(hb);
                float dx = fa.x - fb.x, dy = fa.y - fb.y;
                float l2 = dx * dx + dy * dy;
                s2 += l2; s1 += sqrtf(l2);
            }
            {
                __half2 ha = *reinterpret_cast<__half2*>(&pa2);
                __half2 hb = *reinterpret_cast<__half2*>(&pb2);
                float2 fa = __half22float2(ha);
                float2 fb = __half22float2(hb);
                float dx = fa.x - fb.x, dy = fa.y - fb.y;
                float l2 = dx * dx + dy * dy;
                s2 += l2; s1 += sqrtf(l2);
            }
            {
                __half2 ha = *reinterpret_cast<__half2*>(&pa3);
                __half2 hb = *reinterpret_cast<__half2*>(&pb3);
                float2 fa = __half22float2(ha);
                float2 fb = __half22float2(hb);
                float dx = fa.x - fb.x, dy = fa.y - fb.y;
                float l2 = dx * dx + dy * dy;
                s2 += l2; s1 += sqrtf(l2);
            }
            if (!more) break;
            g = gn; a = an; b = bn;
        }
    }
    edge_flush(s1, s2, ws, edge_mode, smem1, smem2);
}

__global__ void edge_pass_f32(const float2* __restrict__ pred,
                              const int* __restrict__ ei,
                              double* __restrict__ ws,
                              int edge_mode) {
    __shared__ double smem1[8];
    __shared__ double smem2[8];

    float s1 = 0.f, s2 = 0.f;
    const int idx = blockIdx.x * blockDim.x + threadIdx.x;
    const int stride = gridDim.x * blockDim.x;
    for (int e = idx; e < N_EDGES; e += stride) {
        int i = ei[e];
        int j = ei[N_EDGES + e];
        float2 pi = pred[i];
        float2 pj = pred[j];
        float dx = pi.x - pj.x, dy = pi.y - pj.y;
        float l2 = dx * dx + dy * dy;
        s2 += l2;
        s1 += sqrtf(l2);
    }
    edge_flush(s1, s2, ws, edge_mode, smem1, smem2);
}

__global__ void finalize(const double* __restrict__ ws,
                         const int* __restrict__ epoch_p,
                         float* __restrict__ out,
                         int ns, int edge_mode) {
    double recon_sum = 0.0, kl_sum = 0.0;
    for (int s = 0; s < ns; ++s) {
        recon_sum += ws[SH_BASE + s * SH_STRIDE + 0];
        kl_sum    += ws[SH_BASE + s * SH_STRIDE + 1];
    }
    double S1, S2;
    if (edge_mode) {
        S1 = 0.0; S2 = 0.0;
        for (int s = 0; s < EDGE_NSHADOW; ++s) {
            S1 += ws[EDGE_SH_BASE + s * 8 + 0];
            S2 += ws[EDGE_SH_BASE + s * 8 + 1];
        }
    } else {
        S1 = ws[1]; S2 = ws[2];
    }
    double recon = recon_sum / (2.0 * (double)N_NODES);
    double lap  = S2 / (double)N_EDGES;
    double arap = (S2 - S1 * S1 / (double)N_EDGES) / ((double)N_EDGES - 1.0);
    double drift = 0.0;
    for (int g = 0; g < NUM_GRAPHS; ++g) {
        double c = 0.0, sx = 0.0, sy = 0.0;
        for (int s = 0; s < ns; ++s) {
            c  += ws[SH_BASE + s * SH_STRIDE + 130 + g];
            sx += ws[SH_BASE + s * SH_STRIDE + 2 + g];
            sy += ws[SH_BASE + s * SH_STRIDE + 66 + g];
        }
        double mx = sx / c, my = sy / c;
        drift += mx * mx + my * my;
    }
    drift /= (double)NUM_GRAPHS;
    double kl = -0.5 * kl_sum / (double)NUM_GRAPHS;
    int epoch = *epoch_p;
    double beta = (epoch < 10) ? ((double)epoch / 10.0) : 1.0;
    out[0] = (float)(recon + 0.1 * lap + 0.01 * drift + 0.1 * arap + beta * kl);
}

extern "C" void kernel_launch(void* const* d_in, const int* in_sizes, int n_in,
                              void* d_out, int out_size, void* d_ws, size_t ws_size,
                              hipStream_t stream) {
    const float2* pred   = (const float2*)d_in[0];
    const float2* targ   = (const float2*)d_in[1];
    const int*    ei     = (const int*)d_in[2];
    const int*    batch  = (const int*)d_in[3];
    const float*  mu     = (const float*)d_in[4];
    const float*  logvar = (const float*)d_in[5];
    const int*    epoch  = (const int*)d_in[6];
    float* out = (float*)d_out;
    double* ws = (double*)d_ws;

    const size_t packed_bytes = 4ull * N_NODES;

    if (ws_size >= (size_t)PACKED_OFFSET_BIG + packed_bytes) {
        unsigned* packed = (unsigned*)((char*)d_ws + PACKED_OFFSET_BIG);
        // try single fused cooperative dispatch
        void* args[] = { (void*)&pred, (void*)&targ, (void*)&ei,
                         (void*)&batch, (void*)&mu, (void*)&logvar,
                         (void*)&epoch, (void*)&out, (void*)&ws,
                         (void*)&packed };
        hipError_t err = hipLaunchCooperativeKernel(
            (const void*)fused_all, dim3(2048), dim3(256), args, 0, stream);
        if (err == hipSuccess) return;
        // fall back to the proven 4-launch path
        init_ws<<<(WS_DOUBLES_TOT + 255) / 256, 256, 0, stream>>>(
            ws, WS_DOUBLES_TOT);
        node_kl_pass<<<2048, 256, 0, stream>>>(pred, targ, batch, mu, logvar,
                                               ws, packed, NSHADOW_BIG);
        edge_pass_packed<<<2048, 256, 0, stream>>>(packed, ei, ws, 1);
        finalize<<<1, 1, 0, stream>>>(ws, epoch, out, NSHADOW_BIG, 1);
        return;
    }

    // legacy small-ws path
    int ns = 1, edge_mode = 0;
    unsigned* packed = (ws_size >= (size_t)PACKED_OFFSET_LEGACY + packed_bytes)
        ? (unsigned*)((char*)d_ws + PACKED_OFFSET_LEGACY) : (unsigned*)nullptr;
    init_ws<<<1, 256, 0, stream>>>(ws, WS_DOUBLES_LEGACY);
    node_kl_pass<<<2048, 256, 0, stream>>>(pred, targ, batch, mu, logvar, ws,
                                           packed, ns);
    if (packed)
        edge_pass_packed<<<2048, 256, 0, stream>>>(packed, ei, ws, edge_mode);
    else
        edge_pass_f32<<<2048, 256, 0, stream>>>(pred, ei, ws, edge_mode);
    finalize<<<1, 1, 0, stream>>>(ws, epoch, out, ns, edge_mode);
}

// Round 16
// 392.893 us; speedup vs baseline: 2.9782x; 2.9782x over previous
//
#include <hip/hip_runtime.h>
#include <hip/hip_fp16.h>
#include <math.h>

#define N_NODES    1000000
#define N_EDGES    16000000
#define NUM_GRAPHS 64
#define LATENT     128

// ws layout (doubles):
// [0..4): legacy scalars: [1] S1 [2] S2 (legacy edge mode)
// node shadow region: 8 copies at SH_BASE + s*SH_STRIDE:
//   +0 recon, +1 kl, +2..66 gx, +66..130 gy, +130..194 cnt
// edge shadows (big mode): 16 line-separated {S1,S2} pairs at EDGE_SH_BASE + sh*8
// packed half2 table at byte offset 16384 (big mode) or 2048 (legacy mode)
#define SH_BASE        8
#define SH_STRIDE      200
#define NSHADOW_BIG    8
#define EDGE_SH_BASE   1608   // 8 + 8*200
#define EDGE_NSHADOW   16
#define WS_DOUBLES_TOT 1736   // 1608 + 16*8
#define WS_DOUBLES_LEGACY 208
#define PACKED_OFFSET_BIG    16384
#define PACKED_OFFSET_LEGACY 2048

typedef int vint4 __attribute__((ext_vector_type(4)));

// NOTE (round-15 lesson): a single cooperative mega-kernel with 3
// grid.sync()s measured 1029 µs vs this 4-launch structure's ~230 µs of
// kernel time — grid-wide sync at 2048 blocks on 8 non-coherent XCDs
// costs O(100 µs) per sync. Do not re-fuse.

__global__ void init_ws(double* ws, int n) {
    int t = blockIdx.x * blockDim.x + threadIdx.x;
    if (t < n) ws[t] = 0.0;
}

// Wave-contiguous node pass: each wave owns a contiguous ~123-node chunk
// (coalesced loads; a thread's nodes lie in ONE graph almost always).
// Per-thread accumulators flush to LDS only on graph change / at end.
__global__ void node_kl_pass(const float2* __restrict__ pred,
                             const float2* __restrict__ targ,
                             const int*    __restrict__ batch,
                             const float*  __restrict__ mu,
                             const float*  __restrict__ logvar,
                             double* __restrict__ ws,
                             unsigned* __restrict__ packed,  // may be null
                             int ns) {
    __shared__ float sgx[NUM_GRAPHS];
    __shared__ float sgy[NUM_GRAPHS];
    __shared__ int   scnt[NUM_GRAPHS];
    __shared__ double smem[8];

    for (int g = threadIdx.x; g < NUM_GRAPHS; g += blockDim.x) {
        sgx[g] = 0.f; sgy[g] = 0.f; scnt[g] = 0;
    }
    __syncthreads();

    double* shbase = ws + SH_BASE + (size_t)(blockIdx.x & (ns - 1)) * SH_STRIDE;

    const int lane   = threadIdx.x & 63;
    const int wid    = threadIdx.x >> 6;
    const int nwaves = (gridDim.x * blockDim.x) >> 6;
    const int gwave  = (blockIdx.x * blockDim.x + threadIdx.x) >> 6;
    const int chunk  = (N_NODES + nwaves - 1) / nwaves;
    const int start  = gwave * chunk;
    const int end    = (start + chunk < N_NODES) ? (start + chunk) : N_NODES;

    float recon = 0.f, sx = 0.f, sy = 0.f;
    int cnt = 0, bcur = -1;
    for (int n0 = start; n0 < end; n0 += 64) {
        const int n = n0 + lane;
        if (n < end) {
            float2 p = pred[n];
            float2 t = targ[n];
            float dx = p.x - t.x, dy = p.y - t.y;
            recon += dx * dx + dy * dy;
            if (packed) {
                __half2 h = __floats2half2_rn(p.x, p.y);
                packed[n] = *reinterpret_cast<unsigned*>(&h);
            }
            int b = batch[n];
            if (b != bcur) {
                if (cnt != 0) {
                    atomicAdd(&sgx[bcur], sx);
                    atomicAdd(&sgy[bcur], sy);
                    atomicAdd(&scnt[bcur], cnt);
                }
                bcur = b; sx = 0.f; sy = 0.f; cnt = 0;
            }
            sx += p.x; sy += p.y; ++cnt;
        }
    }
    if (cnt != 0) {
        atomicAdd(&sgx[bcur], sx);
        atomicAdd(&sgy[bcur], sy);
        atomicAdd(&scnt[bcur], cnt);
    }

    double r = (double)recon;
    #pragma unroll
    for (int off = 32; off > 0; off >>= 1) r += __shfl_down(r, off);
    if (lane == 0) smem[wid] = r;
    __syncthreads();
    if (threadIdx.x == 0) {
        double tot = 0.0;
        const int nw = blockDim.x >> 6;
        for (int w = 0; w < nw; ++w) tot += smem[w];
        atomicAdd(&shbase[0], tot);
    }
    for (int g = threadIdx.x; g < NUM_GRAPHS; g += blockDim.x) {
        if (scnt[g] != 0) {
            atomicAdd(&shbase[2 + g],   (double)sgx[g]);
            atomicAdd(&shbase[66 + g],  (double)sgy[g]);
            atomicAdd(&shbase[130 + g], (double)scnt[g]);
        }
    }
    if (blockIdx.x == 0) {
        double s = 0.0;
        for (int t = threadIdx.x; t < NUM_GRAPHS * LATENT; t += blockDim.x) {
            float m = mu[t], lv = logvar[t];
            s += (double)(1.0f + lv - m * m - expf(lv));
        }
        #pragma unroll
        for (int off = 32; off > 0; off >>= 1) s += __shfl_down(s, off);
        __syncthreads();
        if (lane == 0) smem[wid] = s;
        __syncthreads();
        if (threadIdx.x == 0) {
            double tot = 0.0;
            const int nw = blockDim.x >> 6;
            for (int w = 0; w < nw; ++w) tot += smem[w];
            atomicAdd(&shbase[1], tot);
        }
    }
}

__device__ __forceinline__ void edge_flush(float s1, float s2, double* ws,
                                           int edge_mode,
                                           double* smem1, double* smem2) {
    double r1 = (double)s1, r2 = (double)s2;
    #pragma unroll
    for (int off = 32; off > 0; off >>= 1) {
        r1 += __shfl_down(r1, off);
        r2 += __shfl_down(r2, off);
    }
    const int lane = threadIdx.x & 63;
    const int wid  = threadIdx.x >> 6;
    if (lane == 0) { smem1[wid] = r1; smem2[wid] = r2; }
    __syncthreads();
    if (threadIdx.x == 0) {
        double t1 = 0.0, t2 = 0.0;
        const int nw = blockDim.x >> 6;
        for (int w = 0; w < nw; ++w) { t1 += smem1[w]; t2 += smem2[w]; }
        if (edge_mode) {
            const int sh = blockIdx.x & (EDGE_NSHADOW - 1);
            atomicAdd(&ws[EDGE_SH_BASE + sh * 8 + 0], t1);
            atomicAdd(&ws[EDGE_SH_BASE + sh * 8 + 1], t2);
        } else {
            atomicAdd(&ws[1], t1);
            atomicAdd(&ws[2], t2);
        }
    }
}

// ===== Edge pass: measured 156 µs @2048 blocks (round 9) =====
// 4 edges / 8 compiler-tracked gathers per iteration; nontemporal index
// prefetch issued between gathers and consume. sc0-policy and MLP-depth
// variants measured NULL (round-8 factorial): the pass is L2
// random-request bound (~62% of per-XCD channel ceiling, queuing-limited).
__global__ void edge_pass_packed(const unsigned* __restrict__ packed,
                                 const int* __restrict__ ei,
                                 double* __restrict__ ws,
                                 int edge_mode) {
    __shared__ double smem1[8];
    __shared__ double smem2[8];

    float s1 = 0.f, s2 = 0.f;
    const int gid = blockIdx.x * blockDim.x + threadIdx.x;
    const int stride = gridDim.x * blockDim.x;
    const int ngroups = N_EDGES / 4;
    const vint4* eia = (const vint4*)ei;
    const vint4* eib = (const vint4*)(ei + N_EDGES);

    int g = gid;
    if (g < ngroups) {
        vint4 a = __builtin_nontemporal_load(eia + g);
        vint4 b = __builtin_nontemporal_load(eib + g);
        while (true) {
            // 1) issue the 8 gathers for the current group
            unsigned pa0 = packed[a.x], pb0 = packed[b.x];
            unsigned pa1 = packed[a.y], pb1 = packed[b.y];
            unsigned pa2 = packed[a.z], pb2 = packed[b.z];
            unsigned pa3 = packed[a.w], pb3 = packed[b.w];

            // 2) issue next iteration's index loads (prefetch)
            const int gn = g + stride;
            const bool more = gn < ngroups;
            vint4 an = {0, 0, 0, 0}, bn = {0, 0, 0, 0};
            if (more) {
                an = __builtin_nontemporal_load(eia + gn);
                bn = __builtin_nontemporal_load(eib + gn);
            }

            // 3) consume gathers (counted waits leave prefetch in flight)
            {
                __half2 ha = *reinterpret_cast<__half2*>(&pa0);
                __half2 hb = *reinterpret_cast<__half2*>(&pb0);
                float2 fa = __half22float2(ha);
                float2 fb = __half22float2(hb);
                float dx = fa.x - fb.x, dy = fa.y - fb.y;
                float l2 = dx * dx + dy * dy;
                s2 += l2; s1 += sqrtf(l2);
            }
            {
                __half2 ha = *reinterpret_cast<__half2*>(&pa1);
                __half2 hb = *reinterpret_cast<__half2*>(&pb1);
                float2 fa = __half22float2(ha);
                float2 fb = __half22float2(hb);
                float dx = fa.x - fb.x, dy = fa.y - fb.y;
                float l2 = dx * dx + dy * dy;
                s2 += l2; s1 += sqrtf(l2);
            }
            {
                __half2 ha = *reinterpret_cast<__half2*>(&pa2);
                __half2 hb = *reinterpret_cast<__half2*>(&pb2);
                float2 fa = __half22float2(ha);
                float2 fb = __half22float2(hb);
                float dx = fa.x - fb.x, dy = fa.y - fb.y;
                float l2 = dx * dx + dy * dy;
                s2 += l2; s1 += sqrtf(l2);
            }
            {
                __half2 ha = *reinterpret_cast<__half2*>(&pa3);
                __half2 hb = *reinterpret_cast<__half2*>(&pb3);
                float2 fa = __half22float2(ha);
                float2 fb = __half22float2(hb);
                float dx = fa.x - fb.x, dy = fa.y - fb.y;
                float l2 = dx * dx + dy * dy;
                s2 += l2; s1 += sqrtf(l2);
            }

            if (!more) break;
            g = gn; a = an; b = bn;
        }
    }
    edge_flush(s1, s2, ws, edge_mode, smem1, smem2);
}

// Fallback (ws too small for packed table): original float2 gathers.
__global__ void edge_pass_f32(const float2* __restrict__ pred,
                              const int* __restrict__ ei,
                              double* __restrict__ ws,
                              int edge_mode) {
    __shared__ double smem1[8];
    __shared__ double smem2[8];

    float s1 = 0.f, s2 = 0.f;
    const int idx = blockIdx.x * blockDim.x + threadIdx.x;
    const int stride = gridDim.x * blockDim.x;
    for (int e = idx; e < N_EDGES; e += stride) {
        int i = ei[e];
        int j = ei[N_EDGES + e];
        float2 pi = pred[i];
        float2 pj = pred[j];
        float dx = pi.x - pj.x, dy = pi.y - pj.y;
        float l2 = dx * dx + dy * dy;
        s2 += l2;
        s1 += sqrtf(l2);
    }
    edge_flush(s1, s2, ws, edge_mode, smem1, smem2);
}

__global__ void finalize(const double* __restrict__ ws,
                         const int* __restrict__ epoch_p,
                         float* __restrict__ out,
                         int ns, int edge_mode) {
    double recon_sum = 0.0, kl_sum = 0.0;
    for (int s = 0; s < ns; ++s) {
        recon_sum += ws[SH_BASE + s * SH_STRIDE + 0];
        kl_sum    += ws[SH_BASE + s * SH_STRIDE + 1];
    }
    double S1, S2;
    if (edge_mode) {
        S1 = 0.0; S2 = 0.0;
        for (int s = 0; s < EDGE_NSHADOW; ++s) {
            S1 += ws[EDGE_SH_BASE + s * 8 + 0];
            S2 += ws[EDGE_SH_BASE + s * 8 + 1];
        }
    } else {
        S1 = ws[1]; S2 = ws[2];
    }
    double recon = recon_sum / (2.0 * (double)N_NODES);
    double lap  = S2 / (double)N_EDGES;
    double arap = (S2 - S1 * S1 / (double)N_EDGES) / ((double)N_EDGES - 1.0);
    double drift = 0.0;
    for (int g = 0; g < NUM_GRAPHS; ++g) {
        double c = 0.0, sx = 0.0, sy = 0.0;
        for (int s = 0; s < ns; ++s) {
            c  += ws[SH_BASE + s * SH_STRIDE + 130 + g];
            sx += ws[SH_BASE + s * SH_STRIDE + 2 + g];
            sy += ws[SH_BASE + s * SH_STRIDE + 66 + g];
        }
        double mx = sx / c, my = sy / c;
        drift += mx * mx + my * my;
    }
    drift /= (double)NUM_GRAPHS;
    double kl = -0.5 * kl_sum / (double)NUM_GRAPHS;
    int epoch = *epoch_p;
    double beta = (epoch < 10) ? ((double)epoch / 10.0) : 1.0;
    out[0] = (float)(recon + 0.1 * lap + 0.01 * drift + 0.1 * arap + beta * kl);
}

extern "C" void kernel_launch(void* const* d_in, const int* in_sizes, int n_in,
                              void* d_out, int out_size, void* d_ws, size_t ws_size,
                              hipStream_t stream) {
    const float2* pred   = (const float2*)d_in[0];
    const float2* targ   = (const float2*)d_in[1];
    const int*    ei     = (const int*)d_in[2];
    const int*    batch  = (const int*)d_in[3];
    const float*  mu     = (const float*)d_in[4];
    const float*  logvar = (const float*)d_in[5];
    const int*    epoch  = (const int*)d_in[6];
    float* out = (float*)d_out;
    double* ws = (double*)d_ws;

    const size_t packed_bytes = 4ull * N_NODES;
    int ns, edge_mode;
    unsigned* packed;
    if (ws_size >= (size_t)PACKED_OFFSET_BIG + packed_bytes) {
        ns = NSHADOW_BIG; edge_mode = 1;
        packed = (unsigned*)((char*)d_ws + PACKED_OFFSET_BIG);
    } else if (ws_size >= (size_t)PACKED_OFFSET_LEGACY + packed_bytes) {
        ns = 1; edge_mode = 0;
        packed = (unsigned*)((char*)d_ws + PACKED_OFFSET_LEGACY);
    } else {
        ns = 1; edge_mode = 0;
        packed = nullptr;
    }
    const int nz = edge_mode ? WS_DOUBLES_TOT : WS_DOUBLES_LEGACY;

    init_ws<<<(nz + 255) / 256, 256, 0, stream>>>(ws, nz);
    node_kl_pass<<<2048, 256, 0, stream>>>(pred, targ, batch, mu, logvar, ws,
                                           packed, ns);
    if (packed)
        edge_pass_packed<<<2048, 256, 0, stream>>>(packed, ei, ws, edge_mode);
    else
        edge_pass_f32<<<2048, 256, 0, stream>>>(pred, ei, ws, edge_mode);
    finalize<<<1, 1, 0, stream>>>(ws, epoch, out, ns, edge_mode);
}